// Round 5
// baseline (718.843 us; speedup 1.0000x reference)
//
#include <hip/hip_runtime.h>
#include <hip/hip_bf16.h>
#include <math.h>

// Shapes: BSZ=64, A_NUM=2, N_LAYER=4, DIM0=64, DIM1=256, SD0=SD1=64, K_OUT=8, UPS=4
// Middle-section algebra: x(layer) = G ⊙ C with C[b,h] complex scalar, C(0)=1.
//   branch: I = W·(C⊙G) (64x64 complex GEMM over h), E = (1+log|I|^2)·conj(I),
//           Z = W^T·E, w[h] = Σ_w G[h,w]·Z[h,w], branch phasor = conj(w)/|w|,
//   C_new = Σ_j phasor_j · Wc[j].

// ---------------- K0: combined input weights + C init ----------------
__global__ void k0_prep(const float* __restrict__ Wr, const float* __restrict__ Wi,
                        const float* __restrict__ pr, const float* __restrict__ pi,
                        float* __restrict__ ArT, float* __restrict__ AiT,
                        float2* __restrict__ C) {
    int w  = blockIdx.x;    // 0..63   (SD1)
    int w2 = threadIdx.x;   // 0..255  (DIM1)
    float p0r = pr[0], p1r = pr[1], p0i = pi[0], p1i = pi[1];
    float wr0 = Wr[w2 * 64 + w],         wi0 = Wi[w2 * 64 + w];
    float wr1 = Wr[(256 + w2) * 64 + w], wi1 = Wi[(256 + w2) * 64 + w];
    // A[w2,w] = sum_a pre[a] * W_in[a*256+w2, w]  (complex)
    ArT[w * 256 + w2] = p0r * wr0 - p0i * wi0 + p1r * wr1 - p1i * wi1;
    AiT[w * 256 + w2] = p0r * wi0 + p0i * wr0 + p1r * wi1 + p1i * wr1;
    if (w2 < 64) C[w * 64 + w2] = make_float2(1.f, 0.f);  // blockIdx.x = b here
}

// ---------------- K1: G[b,h,w2] = sum_w x[b,h,w] * A[w2,w] (complex) ----------------
__global__ __launch_bounds__(256) void k1_G(const float* __restrict__ inp,
                                            const float* __restrict__ ArT,
                                            const float* __restrict__ AiT,
                                            float* __restrict__ Gr, float* __restrict__ Gi) {
    int hc = blockIdx.x;   // 8 row-chunks of 8
    int b  = blockIdx.y;
    int t  = threadIdx.x;  // w2
    __shared__ float sxr[8][64], sxi[8][64];
    int base_r = (b * 2 + 0) * 4096 + hc * 8 * 64;
    int base_i = (b * 2 + 1) * 4096 + hc * 8 * 64;
    for (int k = t; k < 512; k += 256) {
        int r = k >> 6, w = k & 63;
        sxr[r][w] = inp[base_r + r * 64 + w];
        sxi[r][w] = inp[base_i + r * 64 + w];
    }
    __syncthreads();
    float accr[8], acci[8];
#pragma unroll
    for (int r = 0; r < 8; r++) { accr[r] = 0.f; acci[r] = 0.f; }
    for (int k = 0; k < 64; k++) {
        float ar = ArT[k * 256 + t], ai = AiT[k * 256 + t];
#pragma unroll
        for (int r = 0; r < 8; r++) {
            float xr = sxr[r][k], xi = sxi[r][k];
            accr[r] += xr * ar - xi * ai;
            acci[r] += xi * ar + xr * ai;
        }
    }
#pragma unroll
    for (int r = 0; r < 8; r++) {
        int h = hc * 8 + r;
        Gr[(b * 64 + h) * 256 + t] = accr[r];
        Gi[(b * 64 + h) * 256 + t] = acci[r];
    }
}

// ---------------- K2: one phase branch, partial w-sum ----------------
__global__ __launch_bounds__(256) void k2_layer(const float* __restrict__ Gr,
                                                const float* __restrict__ Gi,
                                                const float2* __restrict__ C,
                                                const float* __restrict__ Wmr,
                                                const float* __restrict__ Wmi,
                                                float2* __restrict__ wsum, int layer) {
    int wc = blockIdx.x;  // 4 column chunks of 64
    int j  = blockIdx.y;  // branch
    int b  = blockIdx.z;
    int t = threadIdx.x, tx = t & 63, ty = t >> 6;
    __shared__ float2 sW[4096];  // [c][h] complex
    __shared__ float2 sX[4096];  // [h][w], later reused as E [c][w]
    const float* Wr = Wmr + (layer + 4 * j) * 4096;
    const float* Wi = Wmi + (layer + 4 * j) * 4096;
    for (int k = t; k < 4096; k += 256) sW[k] = make_float2(Wr[k], Wi[k]);

    int gbase = b * 64 * 256 + wc * 64 + tx;
    float gr_[16], gi_[16];
#pragma unroll
    for (int r = 0; r < 16; r++) {
        int h = ty * 16 + r;
        float gr = Gr[gbase + h * 256], gi = Gi[gbase + h * 256];
        gr_[r] = gr; gi_[r] = gi;
        float2 c = C[b * 64 + h];
        sX[h * 64 + tx] = make_float2(c.x * gr - c.y * gi, c.x * gi + c.y * gr);
    }
    __syncthreads();

    // I[c][tx], c = ty*16+r
    float Ir[16], Ii[16];
#pragma unroll
    for (int r = 0; r < 16; r++) { Ir[r] = 0.f; Ii[r] = 0.f; }
    for (int h = 0; h < 64; h++) {
        float2 x = sX[h * 64 + tx];
#pragma unroll
        for (int r = 0; r < 16; r++) {
            float2 w = sW[(ty * 16 + r) * 64 + h];
            Ir[r] += w.x * x.x - w.y * x.y;
            Ii[r] += w.x * x.y + w.y * x.x;
        }
    }
    __syncthreads();
    // E = s * conj(I), s = 1 + log|I|^2 ; store into sX as [c][w]
#pragma unroll
    for (int r = 0; r < 16; r++) {
        float m2 = Ir[r] * Ir[r] + Ii[r] * Ii[r];
        float s = 1.f + __logf(m2);
        sX[(ty * 16 + r) * 64 + tx] = make_float2(s * Ir[r], -s * Ii[r]);
    }
    __syncthreads();

    // Z[h][tx], h = ty*16+r
    float Zr[16], Zi[16];
#pragma unroll
    for (int r = 0; r < 16; r++) { Zr[r] = 0.f; Zi[r] = 0.f; }
    for (int c = 0; c < 64; c++) {
        float2 e = sX[c * 64 + tx];
#pragma unroll
        for (int r = 0; r < 16; r++) {
            float2 w = sW[c * 64 + ty * 16 + r];
            Zr[r] += w.x * e.x - w.y * e.y;
            Zi[r] += w.x * e.y + w.y * e.x;
        }
    }
    // partial w-sum over this 64-column chunk
#pragma unroll
    for (int r = 0; r < 16; r++) {
        int h = ty * 16 + r;
        float pr = gr_[r] * Zr[r] - gi_[r] * Zi[r];
        float pi = gr_[r] * Zi[r] + gi_[r] * Zr[r];
#pragma unroll
        for (int off = 32; off > 0; off >>= 1) {
            pr += __shfl_xor(pr, off);
            pi += __shfl_xor(pi, off);
        }
        if (tx == 0) wsum[((b * 64 + h) * 2 + j) * 4 + wc] = make_float2(pr, pi);
    }
}

// ---------------- K3: C update ----------------
__global__ void k3_cupdate(const float2* __restrict__ wsum, float2* __restrict__ C,
                           const float* __restrict__ Wcr, const float* __restrict__ Wci,
                           int layer) {
    int id = blockIdx.x * 256 + threadIdx.x;  // (b*64+h), 4096 total
    float accr = 0.f, acci = 0.f;
#pragma unroll
    for (int j = 0; j < 2; j++) {
        float wr = 0.f, wi = 0.f;
#pragma unroll
        for (int wc = 0; wc < 4; wc++) {
            float2 p = wsum[(id * 2 + j) * 4 + wc];
            wr += p.x; wi += p.y;
        }
        float m2 = wr * wr + wi * wi;
        float cr, ci;
        if (m2 > 0.f) {
            float inv = 1.f / sqrtf(m2);
            cr = wr * inv; ci = -wi * inv;   // cos(atan2), -sin(atan2)
        } else { cr = 1.f; ci = 0.f; }
        float wcr = Wcr[layer * 2 + j], wci = Wci[layer * 2 + j];
        accr += cr * wcr - ci * wci;
        acci += ci * wcr + cr * wci;
    }
    C[id] = make_float2(accr, acci);
}

// ---------------- K4: final projection |W_l3 · (C⊙G)| + block max ----------------
__global__ __launch_bounds__(256) void k4_proj(const float* __restrict__ Gr,
                                               const float* __restrict__ Gi,
                                               const float2* __restrict__ C,
                                               const float* __restrict__ W3r,
                                               const float* __restrict__ W3i,
                                               float* __restrict__ xmag,
                                               float* __restrict__ pmax) {
    int wc = blockIdx.x;   // 4 col chunks
    int cb = blockIdx.y;   // 2 c-halves of 64
    int b  = blockIdx.z;
    int t = threadIdx.x, tx = t & 63, ty = t >> 6;
    __shared__ float2 sW[4096];
    __shared__ float2 sX[4096];
    for (int k = t; k < 4096; k += 256)
        sW[k] = make_float2(W3r[cb * 4096 + k], W3i[cb * 4096 + k]);
    int gbase = b * 64 * 256 + wc * 64 + tx;
#pragma unroll
    for (int r = 0; r < 16; r++) {
        int h = ty * 16 + r;
        float gr = Gr[gbase + h * 256], gi = Gi[gbase + h * 256];
        float2 c = C[b * 64 + h];
        sX[h * 64 + tx] = make_float2(c.x * gr - c.y * gi, c.x * gi + c.y * gr);
    }
    __syncthreads();
    float mx = 0.f;
#pragma unroll
    for (int r = 0; r < 16; r++) {
        int cl = ty * 16 + r;
        float fr = 0.f, fi = 0.f;
        for (int h = 0; h < 64; h++) {
            float2 x = sX[h * 64 + tx];
            float2 w = sW[cl * 64 + h];
            fr += w.x * x.x - w.y * x.y;
            fi += w.x * x.y + w.y * x.x;
        }
        float mag = sqrtf(fr * fr + fi * fi);
        xmag[(b * 128 + cb * 64 + cl) * 256 + wc * 64 + tx] = mag;
        mx = fmaxf(mx, mag);
    }
#pragma unroll
    for (int off = 32; off > 0; off >>= 1) mx = fmaxf(mx, __shfl_xor(mx, off));
    __syncthreads();
    float* scratch = (float*)sX;
    if (tx == 0) scratch[ty] = mx;
    __syncthreads();
    if (t == 0)
        pmax[b * 8 + cb * 4 + wc] =
            fmaxf(fmaxf(scratch[0], scratch[1]), fmaxf(scratch[2], scratch[3]));
}

// ---------------- K5: 1/max per batch ----------------
__global__ void k5_invm(const float* __restrict__ pmax, float* __restrict__ invm) {
    int b = threadIdx.x;
    float m = 0.f;
#pragma unroll
    for (int k = 0; k < 8; k++) m = fmaxf(m, pmax[b * 8 + k]);
    invm[b] = 1.f / m;
}

__global__ void k5b_scale(float* __restrict__ x, const float* __restrict__ invm) {
    int id = blockIdx.x * 256 + threadIdx.x;  // 2,097,152
    x[id] *= invm[id >> 15];
}

// ---------------- conv 3x3 circular (+optional bn+relu on input) + partial stats ----------------
__global__ __launch_bounds__(256) void k_conv(const float* __restrict__ xin,
                                              const float* __restrict__ cw,
                                              const float* __restrict__ stats,
                                              float* __restrict__ hout,
                                              float* __restrict__ psum,
                                              float* __restrict__ psumsq,
                                              int layer, int apply_bn_relu) {
    int hb = blockIdx.x;  // 4 row chunks of 16
    int co = blockIdx.y;  // 2
    int b  = blockIdx.z;
    int tx = threadIdx.x;  // column 0..255
    float wgt[18];
    const float* wp = cw + layer * 36 + co * 18;
#pragma unroll
    for (int k = 0; k < 18; k++) wgt[k] = wp[k];
    float sc0 = 1.f, sc1 = 1.f, sh0 = 0.f, sh1 = 0.f;
    if (apply_bn_relu) { sc0 = stats[0]; sc1 = stats[1]; sh0 = stats[2]; sh1 = stats[3]; }
    int wm = (tx + 255) & 255, wpp = (tx + 1) & 255;
    float lsum = 0.f, lsq = 0.f;
    for (int r = 0; r < 16; r++) {
        int hh = hb * 16 + r;
        int hm = (hh + 63) & 63, hp = (hh + 1) & 63;
        const int rows[3] = {hm, hh, hp};
        const int cols[3] = {wm, tx, wpp};
        float acc = 0.f;
#pragma unroll
        for (int ci = 0; ci < 2; ci++) {
            const float* xp = xin + (b * 2 + ci) * 16384;
            float sc = ci ? sc1 : sc0, sh = ci ? sh1 : sh0;
            const float* wg = wgt + ci * 9;
#pragma unroll
            for (int kh = 0; kh < 3; kh++)
#pragma unroll
                for (int kw = 0; kw < 3; kw++) {
                    float v = xp[rows[kh] * 256 + cols[kw]];
                    if (apply_bn_relu) v = fmaxf(v * sc + sh, 0.f);
                    acc += wg[kh * 3 + kw] * v;
                }
        }
        hout[((b * 2 + co) * 64 + hh) * 256 + tx] = acc;
        lsum += acc; lsq += acc * acc;
    }
#pragma unroll
    for (int off = 32; off > 0; off >>= 1) {
        lsum += __shfl_xor(lsum, off);
        lsq  += __shfl_xor(lsq, off);
    }
    __shared__ float ssum[4], ssq[4];
    int ty = tx >> 6, lane = tx & 63;
    if (lane == 0) { ssum[ty] = lsum; ssq[ty] = lsq; }
    __syncthreads();
    if (tx == 0) {
        int bl = b * 4 + hb;
        psum[co * 256 + bl]   = ssum[0] + ssum[1] + ssum[2] + ssum[3];
        psumsq[co * 256 + bl] = ssq[0] + ssq[1] + ssq[2] + ssq[3];
    }
}

// ---------------- stats finalize -> scale/shift ----------------
__global__ void k_stats(const float* __restrict__ psum, const float* __restrict__ psumsq,
                        const float* __restrict__ g, const float* __restrict__ bb,
                        float* __restrict__ stats, int layer) {
    int ch = threadIdx.x >> 6, lane = threadIdx.x & 63;  // 128 threads
    float s = 0.f, q = 0.f;
#pragma unroll
    for (int k = lane; k < 256; k += 64) { s += psum[ch * 256 + k]; q += psumsq[ch * 256 + k]; }
#pragma unroll
    for (int off = 32; off > 0; off >>= 1) { s += __shfl_xor(s, off); q += __shfl_xor(q, off); }
    if (lane == 0) {
        const float N = 1048576.f;
        float mu = s / N;
        float var = q / N - mu * mu;
        float rs = rsqrtf(var + 1e-5f);
        float gamma = g[layer * 2 + ch];
        stats[ch]     = rs * gamma;
        stats[2 + ch] = bb[layer * 2 + ch] - mu * rs * gamma;
    }
}

// ---------------- residual: x = relu(x + bn2(h2)) ----------------
__global__ void k8_res(float* __restrict__ x, const float* __restrict__ h2,
                       const float* __restrict__ stats) {
    int id = blockIdx.x * 256 + threadIdx.x;
    int ch = (id >> 14) & 1;
    float v = x[id] + h2[id] * stats[ch] + stats[2 + ch];
    x[id] = fmaxf(v, 0.f);
}

// ---------------- K9: stride-4 transposed conv 8x8, 2ch -> 1ch ----------------
__global__ void k9_out(const float* __restrict__ x, const float* __restrict__ Wout,
                       float* __restrict__ out) {
    const int TOT = 64 * 257 * 1025;
    int id = blockIdx.x * 256 + threadIdx.x;
    if (id >= TOT) return;
    int b   = id / 263425;
    int rem = id - b * 263425;
    int oh  = rem / 1025;
    int ow  = rem - oh * 1025;
    int kh0 = (5 - oh) & 3;
    int kw0 = (5 - ow) & 3;
    float acc = 0.f;
#pragma unroll
    for (int ah = 0; ah < 2; ah++) {
        int kh = kh0 + 4 * ah;
        int d = oh + kh - 5;
        if (d < 0 || d > 252) continue;
        int rh = d >> 2;
#pragma unroll
        for (int aw = 0; aw < 2; aw++) {
            int kw = kw0 + 4 * aw;
            int e = ow + kw - 5;
            if (e < 0 || e > 1020) continue;
            int rw = e >> 2;
#pragma unroll
            for (int ci = 0; ci < 2; ci++) {
                float wv = Wout[ci * 64 + (7 - kh) * 8 + (7 - kw)];
                acc += wv * x[((b * 2 + ci) * 64 + rh) * 256 + rw];
            }
        }
    }
    out[id] = acc;
}

extern "C" void kernel_launch(void* const* d_in, const int* in_sizes, int n_in,
                              void* d_out, int out_size, void* d_ws, size_t ws_size,
                              hipStream_t stream) {
    const float* inp   = (const float*)d_in[0];
    const float* Winr  = (const float*)d_in[1];
    const float* Wini  = (const float*)d_in[2];
    const float* Wprer = (const float*)d_in[3];
    const float* Wprei = (const float*)d_in[4];
    const float* Wmr   = (const float*)d_in[5];
    const float* Wmi   = (const float*)d_in[6];
    const float* Wcr   = (const float*)d_in[7];
    const float* Wci   = (const float*)d_in[8];
    const float* W3r   = (const float*)d_in[9];
    const float* W3i   = (const float*)d_in[10];
    const float* cw1   = (const float*)d_in[11];
    const float* bn1g  = (const float*)d_in[12];
    const float* bn1b  = (const float*)d_in[13];
    const float* cw2   = (const float*)d_in[14];
    const float* bn2g  = (const float*)d_in[15];
    const float* bn2b  = (const float*)d_in[16];
    const float* Wout  = (const float*)d_in[17];
    float* out = (float*)d_out;

    float* ws = (float*)d_ws;
    float*  ArT   = ws;                         // 16384
    float*  AiT   = ArT + 16384;                // 16384
    float2* C     = (float2*)(AiT + 16384);     // 4096 f2
    float*  Gr    = (float*)C + 8192;           // 1048576
    float*  Gi    = Gr + 1048576;               // 1048576
    float2* wsum  = (float2*)(Gi + 1048576);    // 32768 f2
    float*  xmag  = (float*)wsum + 65536;       // 2097152
    float*  h2    = xmag + 2097152;             // 2097152
    float*  pmax  = h2 + 2097152;               // 512
    float*  invm  = pmax + 512;                 // 64
    float*  psum1 = invm + 64;                  // 512
    float*  psq1  = psum1 + 512;                // 512
    float*  psum2 = psq1 + 512;                 // 512
    float*  psq2  = psum2 + 512;                // 512
    float*  stats = psq2 + 512;                 // 8 (bn1: 0..3, bn2: 4..7)
    float*  h1    = Gr;  // overlay: G dead after k4_proj

    k0_prep<<<64, 256, 0, stream>>>(Winr, Wini, Wprer, Wprei, ArT, AiT, C);
    k1_G<<<dim3(8, 64), 256, 0, stream>>>(inp, ArT, AiT, Gr, Gi);
    for (int i = 0; i < 4; i++) {
        k2_layer<<<dim3(4, 2, 64), 256, 0, stream>>>(Gr, Gi, C, Wmr, Wmi, wsum, i);
        k3_cupdate<<<16, 256, 0, stream>>>(wsum, C, Wcr, Wci, i);
    }
    k4_proj<<<dim3(4, 2, 64), 256, 0, stream>>>(Gr, Gi, C, W3r, W3i, xmag, pmax);
    k5_invm<<<1, 64, 0, stream>>>(pmax, invm);
    k5b_scale<<<8192, 256, 0, stream>>>(xmag, invm);
    for (int i = 0; i < 4; i++) {
        k_conv<<<dim3(4, 2, 64), 256, 0, stream>>>(xmag, cw1, stats, h1, psum1, psq1, i, 0);
        k_stats<<<1, 128, 0, stream>>>(psum1, psq1, bn1g, bn1b, stats, i);
        k_conv<<<dim3(4, 2, 64), 256, 0, stream>>>(h1, cw2, stats, h2, psum2, psq2, i, 1);
        k_stats<<<1, 128, 0, stream>>>(psum2, psq2, bn2g, bn2b, stats + 4, i);
        k8_res<<<8192, 256, 0, stream>>>(xmag, h2, stats + 4);
    }
    k9_out<<<65857, 256, 0, stream>>>(xmag, Wout, out);
}

// Round 6
// 559.860 us; speedup vs baseline: 1.2840x; 1.2840x over previous
//
#include <hip/hip_runtime.h>
#include <hip/hip_bf16.h>
#include <math.h>

// Shapes: BSZ=64, A_NUM=2, N_LAYER=4, DIM0=64, DIM1=256, SD0=SD1=64, K_OUT=8, UPS=4
// Middle-section algebra: x(layer) = G ⊙ C with C[b,h] complex scalar, C(0)=1.
// R5: k4 loop-nest fixed (h-outer/r-inner, was a 1024-iter dependent chain = 195us @ 11% VALUBusy);
//     k2/k4 use 1024-thread blocks (16 waves, 4 rows/thread) -> 32 waves/CU vs 8.

// ---------------- K0: combined input weights + C init ----------------
__global__ void k0_prep(const float* __restrict__ Wr, const float* __restrict__ Wi,
                        const float* __restrict__ pr, const float* __restrict__ pi,
                        float* __restrict__ ArT, float* __restrict__ AiT,
                        float2* __restrict__ C) {
    int w  = blockIdx.x;    // 0..63   (SD1)
    int w2 = threadIdx.x;   // 0..255  (DIM1)
    float p0r = pr[0], p1r = pr[1], p0i = pi[0], p1i = pi[1];
    float wr0 = Wr[w2 * 64 + w],         wi0 = Wi[w2 * 64 + w];
    float wr1 = Wr[(256 + w2) * 64 + w], wi1 = Wi[(256 + w2) * 64 + w];
    ArT[w * 256 + w2] = p0r * wr0 - p0i * wi0 + p1r * wr1 - p1i * wi1;
    AiT[w * 256 + w2] = p0r * wi0 + p0i * wr0 + p1r * wi1 + p1i * wr1;
    if (w2 < 64) C[w * 64 + w2] = make_float2(1.f, 0.f);  // blockIdx.x = b here
}

// ---------------- K1: G[b,h,w2] = sum_w x[b,h,w] * A[w2,w] (complex) ----------------
__global__ __launch_bounds__(256) void k1_G(const float* __restrict__ inp,
                                            const float* __restrict__ ArT,
                                            const float* __restrict__ AiT,
                                            float* __restrict__ Gr, float* __restrict__ Gi) {
    int hc = blockIdx.x;   // 8 row-chunks of 8
    int b  = blockIdx.y;
    int t  = threadIdx.x;  // w2
    __shared__ float sxr[8][64], sxi[8][64];
    int base_r = (b * 2 + 0) * 4096 + hc * 8 * 64;
    int base_i = (b * 2 + 1) * 4096 + hc * 8 * 64;
    for (int k = t; k < 512; k += 256) {
        int r = k >> 6, w = k & 63;
        sxr[r][w] = inp[base_r + r * 64 + w];
        sxi[r][w] = inp[base_i + r * 64 + w];
    }
    __syncthreads();
    float accr[8], acci[8];
#pragma unroll
    for (int r = 0; r < 8; r++) { accr[r] = 0.f; acci[r] = 0.f; }
    for (int k = 0; k < 64; k++) {
        float ar = ArT[k * 256 + t], ai = AiT[k * 256 + t];
#pragma unroll
        for (int r = 0; r < 8; r++) {
            float xr = sxr[r][k], xi = sxi[r][k];
            accr[r] += xr * ar - xi * ai;
            acci[r] += xi * ar + xr * ai;
        }
    }
#pragma unroll
    for (int r = 0; r < 8; r++) {
        int h = hc * 8 + r;
        Gr[(b * 64 + h) * 256 + t] = accr[r];
        Gi[(b * 64 + h) * 256 + t] = acci[r];
    }
}

// ---------------- K2: one phase branch, partial w-sum (1024 thr, 4 rows/thr) ----------------
__global__ __launch_bounds__(1024) void k2_layer(const float* __restrict__ Gr,
                                                 const float* __restrict__ Gi,
                                                 const float2* __restrict__ C,
                                                 const float* __restrict__ Wmr,
                                                 const float* __restrict__ Wmi,
                                                 float2* __restrict__ wsum, int layer) {
    int wc = blockIdx.x;  // 4 column chunks of 64
    int j  = blockIdx.y;  // branch
    int b  = blockIdx.z;
    int t = threadIdx.x, tx = t & 63, ty = t >> 6;  // ty 0..15
    __shared__ float2 sW[4096];  // [c][h] complex
    __shared__ float2 sX[4096];  // [h][w], later reused as E [c][w]
    const float* Wr = Wmr + (layer + 4 * j) * 4096;
    const float* Wi = Wmi + (layer + 4 * j) * 4096;
    for (int k = t; k < 4096; k += 1024) sW[k] = make_float2(Wr[k], Wi[k]);

    int gbase = b * 64 * 256 + wc * 64 + tx;
    float gr_[4], gi_[4];
#pragma unroll
    for (int r = 0; r < 4; r++) {
        int h = ty * 4 + r;
        float gr = Gr[gbase + h * 256], gi = Gi[gbase + h * 256];
        gr_[r] = gr; gi_[r] = gi;
        float2 c = C[b * 64 + h];
        sX[h * 64 + tx] = make_float2(c.x * gr - c.y * gi, c.x * gi + c.y * gr);
    }
    __syncthreads();

    // I[c][tx], c = ty*4+r  (h-outer, r-inner: 4 independent acc pairs)
    float Ir[4], Ii[4];
#pragma unroll
    for (int r = 0; r < 4; r++) { Ir[r] = 0.f; Ii[r] = 0.f; }
    for (int h = 0; h < 64; h++) {
        float2 x = sX[h * 64 + tx];
#pragma unroll
        for (int r = 0; r < 4; r++) {
            float2 w = sW[(ty * 4 + r) * 64 + h];
            Ir[r] += w.x * x.x - w.y * x.y;
            Ii[r] += w.x * x.y + w.y * x.x;
        }
    }
    __syncthreads();
    // E = s * conj(I), s = 1 + log|I|^2 ; store into sX as [c][w]
#pragma unroll
    for (int r = 0; r < 4; r++) {
        float m2 = Ir[r] * Ir[r] + Ii[r] * Ii[r];
        float s = 1.f + __logf(m2);
        sX[(ty * 4 + r) * 64 + tx] = make_float2(s * Ir[r], -s * Ii[r]);
    }
    __syncthreads();

    // Z[h][tx], h = ty*4+r
    float Zr[4], Zi[4];
#pragma unroll
    for (int r = 0; r < 4; r++) { Zr[r] = 0.f; Zi[r] = 0.f; }
    for (int c = 0; c < 64; c++) {
        float2 e = sX[c * 64 + tx];
#pragma unroll
        for (int r = 0; r < 4; r++) {
            float2 w = sW[c * 64 + ty * 4 + r];
            Zr[r] += w.x * e.x - w.y * e.y;
            Zi[r] += w.x * e.y + w.y * e.x;
        }
    }
    // partial w-sum over this 64-column chunk
#pragma unroll
    for (int r = 0; r < 4; r++) {
        int h = ty * 4 + r;
        float pr = gr_[r] * Zr[r] - gi_[r] * Zi[r];
        float pi = gr_[r] * Zi[r] + gi_[r] * Zr[r];
#pragma unroll
        for (int off = 32; off > 0; off >>= 1) {
            pr += __shfl_xor(pr, off);
            pi += __shfl_xor(pi, off);
        }
        if (tx == 0) wsum[((b * 64 + h) * 2 + j) * 4 + wc] = make_float2(pr, pi);
    }
}

// ---------------- K3: C update ----------------
__global__ void k3_cupdate(const float2* __restrict__ wsum, float2* __restrict__ C,
                           const float* __restrict__ Wcr, const float* __restrict__ Wci,
                           int layer) {
    int id = blockIdx.x * 256 + threadIdx.x;  // (b*64+h), 4096 total
    float accr = 0.f, acci = 0.f;
#pragma unroll
    for (int j = 0; j < 2; j++) {
        float wr = 0.f, wi = 0.f;
#pragma unroll
        for (int wc = 0; wc < 4; wc++) {
            float2 p = wsum[(id * 2 + j) * 4 + wc];
            wr += p.x; wi += p.y;
        }
        float m2 = wr * wr + wi * wi;
        float cr, ci;
        if (m2 > 0.f) {
            float inv = 1.f / sqrtf(m2);
            cr = wr * inv; ci = -wi * inv;   // cos(atan2), -sin(atan2)
        } else { cr = 1.f; ci = 0.f; }
        float wcr = Wcr[layer * 2 + j], wci = Wci[layer * 2 + j];
        accr += cr * wcr - ci * wci;
        acci += ci * wcr + cr * wci;
    }
    C[id] = make_float2(accr, acci);
}

// ---------------- K4: final projection |W_l3 · (C⊙G)| + block max (1024 thr) ----------------
__global__ __launch_bounds__(1024) void k4_proj(const float* __restrict__ Gr,
                                                const float* __restrict__ Gi,
                                                const float2* __restrict__ C,
                                                const float* __restrict__ W3r,
                                                const float* __restrict__ W3i,
                                                float* __restrict__ xmag,
                                                float* __restrict__ pmax) {
    int wc = blockIdx.x;   // 4 col chunks
    int cb = blockIdx.y;   // 2 c-halves of 64
    int b  = blockIdx.z;
    int t = threadIdx.x, tx = t & 63, ty = t >> 6;  // ty 0..15
    __shared__ float2 sW[4096];
    __shared__ float2 sX[4096];
    for (int k = t; k < 4096; k += 1024)
        sW[k] = make_float2(W3r[cb * 4096 + k], W3i[cb * 4096 + k]);
    int gbase = b * 64 * 256 + wc * 64 + tx;
#pragma unroll
    for (int r = 0; r < 4; r++) {
        int h = ty * 4 + r;
        float gr = Gr[gbase + h * 256], gi = Gi[gbase + h * 256];
        float2 c = C[b * 64 + h];
        sX[h * 64 + tx] = make_float2(c.x * gr - c.y * gi, c.x * gi + c.y * gr);
    }
    __syncthreads();
    // F[cl][tx], cl = ty*4+r — h-outer, r-inner (4 independent acc pairs)
    float Fr[4], Fi[4];
#pragma unroll
    for (int r = 0; r < 4; r++) { Fr[r] = 0.f; Fi[r] = 0.f; }
    for (int h = 0; h < 64; h++) {
        float2 x = sX[h * 64 + tx];
#pragma unroll
        for (int r = 0; r < 4; r++) {
            float2 w = sW[(ty * 4 + r) * 64 + h];
            Fr[r] += w.x * x.x - w.y * x.y;
            Fi[r] += w.x * x.y + w.y * x.x;
        }
    }
    float mx = 0.f;
#pragma unroll
    for (int r = 0; r < 4; r++) {
        int cl = ty * 4 + r;
        float mag = sqrtf(Fr[r] * Fr[r] + Fi[r] * Fi[r]);
        xmag[(b * 128 + cb * 64 + cl) * 256 + wc * 64 + tx] = mag;
        mx = fmaxf(mx, mag);
    }
#pragma unroll
    for (int off = 32; off > 0; off >>= 1) mx = fmaxf(mx, __shfl_xor(mx, off));
    __syncthreads();
    float* scratch = (float*)sX;
    if (tx == 0) scratch[ty] = mx;
    __syncthreads();
    if (t == 0) {
        float m = scratch[0];
#pragma unroll
        for (int k = 1; k < 16; k++) m = fmaxf(m, scratch[k]);
        pmax[b * 8 + cb * 4 + wc] = m;
    }
}

// ---------------- K5: 1/max per batch ----------------
__global__ void k5_invm(const float* __restrict__ pmax, float* __restrict__ invm) {
    int b = threadIdx.x;
    float m = 0.f;
#pragma unroll
    for (int k = 0; k < 8; k++) m = fmaxf(m, pmax[b * 8 + k]);
    invm[b] = 1.f / m;
}

__global__ void k5b_scale(float* __restrict__ x, const float* __restrict__ invm) {
    int id = blockIdx.x * 256 + threadIdx.x;  // 2,097,152
    x[id] *= invm[id >> 15];
}

// ---------------- conv 3x3 circular (+optional bn+relu on input) + partial stats ----------------
__global__ __launch_bounds__(256) void k_conv(const float* __restrict__ xin,
                                              const float* __restrict__ cw,
                                              const float* __restrict__ stats,
                                              float* __restrict__ hout,
                                              float* __restrict__ psum,
                                              float* __restrict__ psumsq,
                                              int layer, int apply_bn_relu) {
    int hb = blockIdx.x;  // 4 row chunks of 16
    int co = blockIdx.y;  // 2
    int b  = blockIdx.z;
    int tx = threadIdx.x;  // column 0..255
    float wgt[18];
    const float* wp = cw + layer * 36 + co * 18;
#pragma unroll
    for (int k = 0; k < 18; k++) wgt[k] = wp[k];
    float sc0 = 1.f, sc1 = 1.f, sh0 = 0.f, sh1 = 0.f;
    if (apply_bn_relu) { sc0 = stats[0]; sc1 = stats[1]; sh0 = stats[2]; sh1 = stats[3]; }
    int wm = (tx + 255) & 255, wpp = (tx + 1) & 255;
    float lsum = 0.f, lsq = 0.f;
    for (int r = 0; r < 16; r++) {
        int hh = hb * 16 + r;
        int hm = (hh + 63) & 63, hp = (hh + 1) & 63;
        const int rows[3] = {hm, hh, hp};
        const int cols[3] = {wm, tx, wpp};
        float acc = 0.f;
#pragma unroll
        for (int ci = 0; ci < 2; ci++) {
            const float* xp = xin + (b * 2 + ci) * 16384;
            float sc = ci ? sc1 : sc0, sh = ci ? sh1 : sh0;
            const float* wg = wgt + ci * 9;
#pragma unroll
            for (int kh = 0; kh < 3; kh++)
#pragma unroll
                for (int kw = 0; kw < 3; kw++) {
                    float v = xp[rows[kh] * 256 + cols[kw]];
                    if (apply_bn_relu) v = fmaxf(v * sc + sh, 0.f);
                    acc += wg[kh * 3 + kw] * v;
                }
        }
        hout[((b * 2 + co) * 64 + hh) * 256 + tx] = acc;
        lsum += acc; lsq += acc * acc;
    }
#pragma unroll
    for (int off = 32; off > 0; off >>= 1) {
        lsum += __shfl_xor(lsum, off);
        lsq  += __shfl_xor(lsq, off);
    }
    __shared__ float ssum[4], ssq[4];
    int ty = tx >> 6, lane = tx & 63;
    if (lane == 0) { ssum[ty] = lsum; ssq[ty] = lsq; }
    __syncthreads();
    if (tx == 0) {
        int bl = b * 4 + hb;
        psum[co * 256 + bl]   = ssum[0] + ssum[1] + ssum[2] + ssum[3];
        psumsq[co * 256 + bl] = ssq[0] + ssq[1] + ssq[2] + ssq[3];
    }
}

// ---------------- stats finalize -> scale/shift ----------------
__global__ void k_stats(const float* __restrict__ psum, const float* __restrict__ psumsq,
                        const float* __restrict__ g, const float* __restrict__ bb,
                        float* __restrict__ stats, int layer) {
    int ch = threadIdx.x >> 6, lane = threadIdx.x & 63;  // 128 threads
    float s = 0.f, q = 0.f;
#pragma unroll
    for (int k = lane; k < 256; k += 64) { s += psum[ch * 256 + k]; q += psumsq[ch * 256 + k]; }
#pragma unroll
    for (int off = 32; off > 0; off >>= 1) { s += __shfl_xor(s, off); q += __shfl_xor(q, off); }
    if (lane == 0) {
        const float N = 1048576.f;
        float mu = s / N;
        float var = q / N - mu * mu;
        float rs = rsqrtf(var + 1e-5f);
        float gamma = g[layer * 2 + ch];
        stats[ch]     = rs * gamma;
        stats[2 + ch] = bb[layer * 2 + ch] - mu * rs * gamma;
    }
}

// ---------------- residual: x = relu(x + bn2(h2)) ----------------
__global__ void k8_res(float* __restrict__ x, const float* __restrict__ h2,
                       const float* __restrict__ stats) {
    int id = blockIdx.x * 256 + threadIdx.x;
    int ch = (id >> 14) & 1;
    float v = x[id] + h2[id] * stats[ch] + stats[2 + ch];
    x[id] = fmaxf(v, 0.f);
}

// ---------------- K9: stride-4 transposed conv 8x8, 2ch -> 1ch ----------------
__global__ void k9_out(const float* __restrict__ x, const float* __restrict__ Wout,
                       float* __restrict__ out) {
    const int TOT = 64 * 257 * 1025;
    int id = blockIdx.x * 256 + threadIdx.x;
    if (id >= TOT) return;
    int b   = id / 263425;
    int rem = id - b * 263425;
    int oh  = rem / 1025;
    int ow  = rem - oh * 1025;
    int kh0 = (5 - oh) & 3;
    int kw0 = (5 - ow) & 3;
    float acc = 0.f;
#pragma unroll
    for (int ah = 0; ah < 2; ah++) {
        int kh = kh0 + 4 * ah;
        int d = oh + kh - 5;
        if (d < 0 || d > 252) continue;
        int rh = d >> 2;
#pragma unroll
        for (int aw = 0; aw < 2; aw++) {
            int kw = kw0 + 4 * aw;
            int e = ow + kw - 5;
            if (e < 0 || e > 1020) continue;
            int rw = e >> 2;
#pragma unroll
            for (int ci = 0; ci < 2; ci++) {
                float wv = Wout[ci * 64 + (7 - kh) * 8 + (7 - kw)];
                acc += wv * x[((b * 2 + ci) * 64 + rh) * 256 + rw];
            }
        }
    }
    out[id] = acc;
}

extern "C" void kernel_launch(void* const* d_in, const int* in_sizes, int n_in,
                              void* d_out, int out_size, void* d_ws, size_t ws_size,
                              hipStream_t stream) {
    const float* inp   = (const float*)d_in[0];
    const float* Winr  = (const float*)d_in[1];
    const float* Wini  = (const float*)d_in[2];
    const float* Wprer = (const float*)d_in[3];
    const float* Wprei = (const float*)d_in[4];
    const float* Wmr   = (const float*)d_in[5];
    const float* Wmi   = (const float*)d_in[6];
    const float* Wcr   = (const float*)d_in[7];
    const float* Wci   = (const float*)d_in[8];
    const float* W3r   = (const float*)d_in[9];
    const float* W3i   = (const float*)d_in[10];
    const float* cw1   = (const float*)d_in[11];
    const float* bn1g  = (const float*)d_in[12];
    const float* bn1b  = (const float*)d_in[13];
    const float* cw2   = (const float*)d_in[14];
    const float* bn2g  = (const float*)d_in[15];
    const float* bn2b  = (const float*)d_in[16];
    const float* Wout  = (const float*)d_in[17];
    float* out = (float*)d_out;

    float* ws = (float*)d_ws;
    float*  ArT   = ws;                         // 16384
    float*  AiT   = ArT + 16384;                // 16384
    float2* C     = (float2*)(AiT + 16384);     // 4096 f2
    float*  Gr    = (float*)C + 8192;           // 1048576
    float*  Gi    = Gr + 1048576;               // 1048576
    float2* wsum  = (float2*)(Gi + 1048576);    // 32768 f2
    float*  xmag  = (float*)wsum + 65536;       // 2097152
    float*  h2    = xmag + 2097152;             // 2097152
    float*  pmax  = h2 + 2097152;               // 512
    float*  invm  = pmax + 512;                 // 64
    float*  psum1 = invm + 64;                  // 512
    float*  psq1  = psum1 + 512;                // 512
    float*  psum2 = psq1 + 512;                 // 512
    float*  psq2  = psum2 + 512;                // 512
    float*  stats = psq2 + 512;                 // 8 (bn1: 0..3, bn2: 4..7)
    float*  h1    = Gr;  // overlay: G dead after k4_proj

    k0_prep<<<64, 256, 0, stream>>>(Winr, Wini, Wprer, Wprei, ArT, AiT, C);
    k1_G<<<dim3(8, 64), 256, 0, stream>>>(inp, ArT, AiT, Gr, Gi);
    for (int i = 0; i < 4; i++) {
        k2_layer<<<dim3(4, 2, 64), 1024, 0, stream>>>(Gr, Gi, C, Wmr, Wmi, wsum, i);
        k3_cupdate<<<16, 256, 0, stream>>>(wsum, C, Wcr, Wci, i);
    }
    k4_proj<<<dim3(4, 2, 64), 1024, 0, stream>>>(Gr, Gi, C, W3r, W3i, xmag, pmax);
    k5_invm<<<1, 64, 0, stream>>>(pmax, invm);
    k5b_scale<<<8192, 256, 0, stream>>>(xmag, invm);
    for (int i = 0; i < 4; i++) {
        k_conv<<<dim3(4, 2, 64), 256, 0, stream>>>(xmag, cw1, stats, h1, psum1, psq1, i, 0);
        k_stats<<<1, 128, 0, stream>>>(psum1, psq1, bn1g, bn1b, stats, i);
        k_conv<<<dim3(4, 2, 64), 256, 0, stream>>>(h1, cw2, stats, h2, psum2, psq2, i, 1);
        k_stats<<<1, 128, 0, stream>>>(psum2, psq2, bn2g, bn2b, stats + 4, i);
        k8_res<<<8192, 256, 0, stream>>>(xmag, h2, stats + 4);
    }
    k9_out<<<65857, 256, 0, stream>>>(xmag, Wout, out);
}